// Round 6
// baseline (127.447 us; speedup 1.0000x reference)
//
#include <hip/hip_runtime.h>

static constexpr int TPB = 256;
static constexpr int NSLICE = 4;   // slices per batch row
static constexpr int SW = 20;      // spart row stride: 14 weighted + 5 geo + pad

using f4 = __attribute__((ext_vector_type(4))) float;

__device__ __forceinline__ float wave_reduce_f32(float v) {
#pragma unroll
    for (int off = 32; off > 0; off >>= 1)
        v += __shfl_down(v, off, 64);
    return v;
}

// ---------------------------------------------------------------------------
// Single fused kernel, grid (NSLICE, B) = 2048 blocks x 256 thr, all
// co-resident (launch_bounds(256,8) -> VGPR<=64, ~1KB LDS -> 8 blocks/CU).
// Phase 1: block (s,b) reduces slice s of row b: 14 weighted moment sums
//          (a over geo_x, b over geo_y) + 5 unweighted geo_x sums; publishes
//          19 doubles via agent-scope atomic stores, then release-adds
//          rowcnt[b].
// Sync:    thread 0 acquire-spins until rowcnt[b]==NSLICE (only needs its OWN
//          row -> emit of early rows overlaps stats of late rows).
// Phase 2: reduce the 4 slice partials, thread 0 does the closed-form 2x2
//          SPD OT solve in f64, broadcast 10 f32 coefficients via LDS, emit
//          f[b,n] = cxx(x^2-Ex2)+cyy(y^2-Ey2)+cxy(xy-Exy)+cx(x-Ex)+cy(y-Ey)
//          for the SAME gx slice read in phase 1 (L1/L2-hot), NT stores.
// ---------------------------------------------------------------------------
__global__ __launch_bounds__(TPB, 8) void kfused(const float* __restrict__ gx,
                                                 const float* __restrict__ gy,
                                                 const float* __restrict__ a,
                                                 const float* __restrict__ bw,
                                                 int N, int B,
                                                 double* __restrict__ spart,
                                                 int* __restrict__ rowcnt,
                                                 float* __restrict__ out) {
    const int s = blockIdx.x;
    const int b = blockIdx.y;
    const int n4   = N / 4;          // float4 groups of the weight rows
    const int per  = n4 / NSLICE;    // groups per slice (1024)
    const int base = s * per;
    const int lane = threadIdx.x & 63, wid = threadIdx.x >> 6;

    const f4* gx4 = reinterpret_cast<const f4*>(gx);
    const f4* gy4 = reinterpret_cast<const f4*>(gy);
    const f4* a4  = reinterpret_cast<const f4*>(a  + (size_t)b * N);
    const f4* b4  = reinterpret_cast<const f4*>(bw + (size_t)b * N);

    // ---- phase 1: slice moment sums (f32 acc, f64 past wave level) ----
    float acc[19];
#pragma unroll
    for (int k = 0; k < 19; k++) acc[k] = 0.0f;

#pragma unroll 4
    for (int i = base + threadIdx.x; i < base + per; i += TPB) {
        f4 av = a4[i];
        f4 bv = b4[i];
        f4 g0 = gx4[2 * i], g1 = gx4[2 * i + 1];
        f4 h0 = gy4[2 * i], h1 = gy4[2 * i + 1];
        float wa[4] = {av[0], av[1], av[2], av[3]};
        float wb[4] = {bv[0], bv[1], bv[2], bv[3]};
        float px[4] = {g0[0], g0[2], g1[0], g1[2]};
        float py[4] = {g0[1], g0[3], g1[1], g1[3]};
        float qx[4] = {h0[0], h0[2], h1[0], h1[2]};
        float qy[4] = {h0[1], h0[3], h1[1], h1[3]};
#pragma unroll
        for (int j = 0; j < 4; j++) {
            float w = wa[j], x = px[j], y = py[j];
            float xx = x * x, xy = x * y, yy = y * y;
            acc[0] += w;
            acc[1] += w * x;
            acc[2] += w * y;
            acc[3] += w * xx;
            acc[4] += w * xy;
            acc[5] += w * yy;
            acc[6] += w * w;
            float v = wb[j], u = qx[j], t = qy[j];
            float vu = v * u, vt = v * t;
            acc[7]  += v;
            acc[8]  += vu;
            acc[9]  += vt;
            acc[10] += vu * u;
            acc[11] += vu * t;
            acc[12] += vt * t;
            acc[13] += v * v;
            // unweighted geo_x moments (for row-mean centering)
            acc[14] += x;
            acc[15] += y;
            acc[16] += xx;
            acc[17] += xy;
            acc[18] += yy;
        }
    }

    __shared__ double red[4][19];
#pragma unroll
    for (int k = 0; k < 19; k++) {
        float v = wave_reduce_f32(acc[k]);
        if (lane == 0) red[wid][k] = (double)v;
    }
    __syncthreads();
    if (threadIdx.x < 19) {
        double v = red[0][threadIdx.x] + red[1][threadIdx.x] +
                   red[2][threadIdx.x] + red[3][threadIdx.x];
        __hip_atomic_store(&spart[((size_t)b * NSLICE + s) * SW + threadIdx.x], v,
                           __ATOMIC_RELAXED, __HIP_MEMORY_SCOPE_AGENT);
    }
    __syncthreads();
    if (threadIdx.x == 0)
        __hip_atomic_fetch_add(rowcnt + b, 1, __ATOMIC_RELEASE, __HIP_MEMORY_SCOPE_AGENT);

    // ---- per-row sync: wait only for THIS row's 4 slice partials ----
    if (threadIdx.x == 0) {
        while (__hip_atomic_load(rowcnt + b, __ATOMIC_ACQUIRE,
                                 __HIP_MEMORY_SCOPE_AGENT) < NSLICE)
            __builtin_amdgcn_s_sleep(1);
    }
    __syncthreads();

    // ---- phase 2: reduce partials, solve, emit ----
    __shared__ double shs[19];
    __shared__ float shc[10];
    if (threadIdx.x < 19) {
        double t = 0;
#pragma unroll
        for (int ss = 0; ss < NSLICE; ss++)
            t += __hip_atomic_load(&spart[((size_t)b * NSLICE + ss) * SW + threadIdx.x],
                                   __ATOMIC_RELAXED, __HIP_MEMORY_SCOPE_AGENT);
        shs[threadIdx.x] = t;
    }
    __syncthreads();

    if (threadIdx.x == 0) {
        double Sa = shs[0],  mx  = shs[1],  my  = shs[2],  Saxx = shs[3],  Saxy = shs[4],  Sayy = shs[5],  Saa = shs[6];
        double Sb = shs[7],  mbx = shs[8],  mby = shs[9],  Sbxx = shs[10], Sbxy = shs[11], Sbyy = shs[12], Sbb = shs[13];
        double invN = 1.0 / (double)N;
        double Ex  = shs[14] * invN, Ey  = shs[15] * invN;
        double Ex2 = shs[16] * invN, Exy = shs[17] * invN, Ey2 = shs[18] * invN;

        double da = 1.0 - Saa, db = 1.0 - Sbb;
        // cov = (Σ w p p' - m m' (2 - Σw)) / denom (exact expansion of centered sum)
        double Caxx = (Saxx - mx * mx * (2.0 - Sa)) / da;
        double Caxy = (Saxy - mx * my * (2.0 - Sa)) / da;
        double Cayy = (Sayy - my * my * (2.0 - Sa)) / da;
        double Cbxx = (Sbxx - mbx * mbx * (2.0 - Sb)) / db;
        double Cbxy = (Sbxy - mbx * mby * (2.0 - Sb)) / db;
        double Cbyy = (Sbyy - mby * mby * (2.0 - Sb)) / db;

        // R = sqrt(cov_a) = (C + sqrt(det C) I) / sqrt(tr C + 2 sqrt(det C))
        double s0 = sqrt(fmax(Caxx * Cayy - Caxy * Caxy, 0.0));
        double t0 = sqrt(Caxx + Cayy + 2.0 * s0);
        double Rxx = (Caxx + s0) / t0, Rxy = Caxy / t0, Ryy = (Cayy + s0) / t0;
        double detR = Rxx * Ryy - Rxy * Rxy;
        double Ixx = Ryy / detR, Ixy = -Rxy / detR, Iyy = Rxx / detR;  // R^{-1}

        // mid = R cov_b R (symmetric)
        double Txx = Cbxx * Rxx + Cbxy * Rxy;
        double Txy = Cbxx * Rxy + Cbxy * Ryy;
        double Tyx = Cbxy * Rxx + Cbyy * Rxy;
        double Tyy = Cbxy * Rxy + Cbyy * Ryy;
        double midxx = Rxx * Txx + Rxy * Tyx;
        double midyy = Rxy * Txy + Ryy * Tyy;
        double midxy = 0.5 * ((Rxx * Txy + Rxy * Tyy) + (Rxy * Txx + Ryy * Tyx));

        // M = sqrt(mid)
        double s1 = sqrt(fmax(midxx * midyy - midxy * midxy, 0.0));
        double t1 = sqrt(midxx + midyy + 2.0 * s1);
        double Mxx = (midxx + s1) / t1, Mxy = midxy / t1, Myy = (midyy + s1) / t1;

        // A = R^{-1} M R^{-1}
        double Uxx = Mxx * Ixx + Mxy * Ixy;
        double Uxy = Mxx * Ixy + Mxy * Iyy;
        double Uyx = Mxy * Ixx + Myy * Ixy;
        double Uyy = Mxy * Ixy + Myy * Iyy;
        double Axx = Ixx * Uxx + Ixy * Uyx;
        double Axy = Ixx * Uxy + Ixy * Uyy;
        double Ayy = Ixy * Uxy + Iyy * Uyy;

        // quadratic-form coefficients; row-mean subtraction cancels the const
        shc[0] = (float)(1.0 - Axx);
        shc[1] = (float)(1.0 - Ayy);
        shc[2] = (float)(-2.0 * Axy);
        shc[3] = (float)(2.0 * (Axx * mx + Axy * my - mbx));
        shc[4] = (float)(2.0 * (Ayy * my + Axy * mx - mby));
        shc[5] = (float)Ex;
        shc[6] = (float)Ey;
        shc[7] = (float)Ex2;
        shc[8] = (float)Exy;
        shc[9] = (float)Ey2;
    }
    __syncthreads();

    const float cxx = shc[0], cyy = shc[1], cxy = shc[2], cx = shc[3], cy = shc[4];
    const float Ex = shc[5], Ey = shc[6], Ex2 = shc[7], Exy = shc[8], Ey2 = shc[9];

    // emit this block's own slice (gx slice is L1/L2-hot from phase 1)
    f4* out4 = reinterpret_cast<f4*>(out + (size_t)b * N);
#pragma unroll
    for (int k = 0; k < 4; k++) {
        int i = base + k * TPB + threadIdx.x;   // f4 index within row
        f4 g0 = gx4[2 * i], g1 = gx4[2 * i + 1];
        float rx[4] = {g0[0], g0[2], g1[0], g1[2]};
        float ry[4] = {g0[1], g0[3], g1[1], g1[3]};
        f4 o;
#pragma unroll
        for (int j = 0; j < 4; j++) {
            float x = rx[j], y = ry[j];
            o[j] = cxx * (x * x - Ex2) + cyy * (y * y - Ey2) + cxy * (x * y - Exy) +
                   cx * (x - Ex) + cy * (y - Ey);
        }
        __builtin_nontemporal_store(o, out4 + i);
    }
}

// ---------------------------------------------------------------------------
extern "C" void kernel_launch(void* const* d_in, const int* in_sizes, int n_in,
                              void* d_out, int out_size, void* d_ws, size_t ws_size,
                              hipStream_t stream) {
    const float* geo_x = (const float*)d_in[0];
    const float* geo_y = (const float*)d_in[1];
    const float* a     = (const float*)d_in[2];
    const float* b     = (const float*)d_in[3];
    float* out = (float*)d_out;

    int N = in_sizes[0] / 2;       // 16384
    int B = in_sizes[2] / N;       // 512

    char* ws = (char*)d_ws;
    int*    rowcnt = (int*)ws;                       // B ints
    double* spart  = (double*)(ws + 4096);           // B*NSLICE*SW doubles

    hipMemsetAsync(rowcnt, 0, (size_t)B * sizeof(int), stream);
    kfused<<<dim3(NSLICE, B), TPB, 0, stream>>>(geo_x, geo_y, a, b, N, B,
                                                spart, rowcnt, out);
}

// Round 7
// 56.479 us; speedup vs baseline: 2.2566x; 2.2566x over previous
//
#include <hip/hip_runtime.h>

static constexpr int TPB = 256;
static constexpr int NSLICE = 8;   // slices per batch-row-pair
static constexpr int ROWS = 2;     // rows per kstats block (geo slice reused)

using f4 = __attribute__((ext_vector_type(4))) float;

__device__ __forceinline__ float wave_reduce_f32(float v) {
#pragma unroll
    for (int off = 32; off > 0; off >>= 1)
        v += __shfl_down(v, off, 64);
    return v;
}

// ---------------------------------------------------------------------------
// Kernel 1: per-(row-pair, slice) weighted moment partial sums.
// Grid (NSLICE, B/ROWS + 1). Block (s, p) handles rows {2p, 2p+1} restricted
// to geo slice s: reads the gx/gy slice ONCE while streaming 2 a-rows and
// 2 b-rows (halves geo L1/L2 traffic vs row-per-block; doubles streaming
// loads in flight per wave). Row pair == gridDim.y-1: unweighted geo_x
// moments -> gpart[s*5+k]. f32 accumulate (8 pts/thread), f64 past wave level.
// spart layout: [b][NSLICE][14] doubles.
// ---------------------------------------------------------------------------
__global__ __launch_bounds__(TPB, 6) void kstats(const float* __restrict__ gx,
                                                 const float* __restrict__ gy,
                                                 const float* __restrict__ a,
                                                 const float* __restrict__ bw,
                                                 int N, int B,
                                                 double* __restrict__ spart,
                                                 double* __restrict__ gpart) {
    const int s = blockIdx.x;
    const int p = blockIdx.y;
    const int n4   = N / 4;          // float4 groups per row
    const int per  = n4 / NSLICE;    // groups per slice
    const int base = s * per;
    const f4* gx4 = reinterpret_cast<const f4*>(gx);
    const int lane = threadIdx.x & 63, wid = threadIdx.x >> 6;

    if (p == gridDim.y - 1) {
        // unweighted geo_x moments for this slice
        float sx = 0, sy = 0, sxx = 0, sxy = 0, syy = 0;
        for (int i = base + threadIdx.x; i < base + per; i += TPB) {
            f4 g0 = gx4[2 * i], g1 = gx4[2 * i + 1];
            float x0 = g0[0], y0 = g0[1], x1 = g0[2], y1 = g0[3];
            float x2 = g1[0], y2 = g1[1], x3 = g1[2], y3 = g1[3];
            sx  += (x0 + x1) + (x2 + x3);
            sy  += (y0 + y1) + (y2 + y3);
            sxx += x0 * x0 + x1 * x1 + x2 * x2 + x3 * x3;
            sxy += x0 * y0 + x1 * y1 + x2 * y2 + x3 * y3;
            syy += y0 * y0 + y1 * y1 + y2 * y2 + y3 * y3;
        }
        float accg[5] = {sx, sy, sxx, sxy, syy};
        __shared__ double redg[4][5];
#pragma unroll
        for (int k = 0; k < 5; k++) {
            float v = wave_reduce_f32(accg[k]);
            if (lane == 0) redg[wid][k] = (double)v;
        }
        __syncthreads();
        if (threadIdx.x < 5)
            gpart[s * 5 + threadIdx.x] = redg[0][threadIdx.x] + redg[1][threadIdx.x] +
                                         redg[2][threadIdx.x] + redg[3][threadIdx.x];
        return;
    }

    const int r0 = p * ROWS;
    const f4* a0 = reinterpret_cast<const f4*>(a  + (size_t)r0 * N);
    const f4* a1 = reinterpret_cast<const f4*>(a  + (size_t)(r0 + 1) * N);
    const f4* b0 = reinterpret_cast<const f4*>(bw + (size_t)r0 * N);
    const f4* b1 = reinterpret_cast<const f4*>(bw + (size_t)(r0 + 1) * N);
    const f4* gy4 = reinterpret_cast<const f4*>(gy);

    float acc[28];
#pragma unroll
    for (int k = 0; k < 28; k++) acc[k] = 0.0f;

#pragma unroll 2
    for (int i = base + threadIdx.x; i < base + per; i += TPB) {
        f4 av0 = a0[i], av1 = a1[i];
        f4 bv0 = b0[i], bv1 = b1[i];
        f4 g0 = gx4[2 * i], g1 = gx4[2 * i + 1];
        f4 h0 = gy4[2 * i], h1 = gy4[2 * i + 1];
        float wa0[4] = {av0[0], av0[1], av0[2], av0[3]};
        float wa1[4] = {av1[0], av1[1], av1[2], av1[3]};
        float wb0[4] = {bv0[0], bv0[1], bv0[2], bv0[3]};
        float wb1[4] = {bv1[0], bv1[1], bv1[2], bv1[3]};
        float px[4] = {g0[0], g0[2], g1[0], g1[2]};
        float py[4] = {g0[1], g0[3], g1[1], g1[3]};
        float qx[4] = {h0[0], h0[2], h1[0], h1[2]};
        float qy[4] = {h0[1], h0[3], h1[1], h1[3]};
#pragma unroll
        for (int j = 0; j < 4; j++) {
            float x = px[j], y = py[j];
            float u = qx[j], t = qy[j];
            float w0 = wa0[j], w1 = wa1[j];
            float v0 = wb0[j], v1 = wb1[j];
            float w0x = w0 * x, w0y = w0 * y;
            acc[0]  += w0;      acc[1]  += w0x;      acc[2]  += w0y;
            acc[3]  += w0x * x; acc[4]  += w0x * y;  acc[5]  += w0y * y;
            acc[6]  += w0 * w0;
            float v0u = v0 * u, v0t = v0 * t;
            acc[7]  += v0;      acc[8]  += v0u;      acc[9]  += v0t;
            acc[10] += v0u * u; acc[11] += v0u * t;  acc[12] += v0t * t;
            acc[13] += v0 * v0;
            float w1x = w1 * x, w1y = w1 * y;
            acc[14] += w1;      acc[15] += w1x;      acc[16] += w1y;
            acc[17] += w1x * x; acc[18] += w1x * y;  acc[19] += w1y * y;
            acc[20] += w1 * w1;
            float v1u = v1 * u, v1t = v1 * t;
            acc[21] += v1;      acc[22] += v1u;      acc[23] += v1t;
            acc[24] += v1u * u; acc[25] += v1u * t;  acc[26] += v1t * t;
            acc[27] += v1 * v1;
        }
    }

    __shared__ double red[4][28];
#pragma unroll
    for (int k = 0; k < 28; k++) {
        float v = wave_reduce_f32(acc[k]);
        if (lane == 0) red[wid][k] = (double)v;
    }
    __syncthreads();
    if (threadIdx.x < 28) {
        int row = threadIdx.x / 14, idx = threadIdx.x % 14;
        spart[(((size_t)(r0 + row)) * NSLICE + s) * 14 + idx] =
            red[0][threadIdx.x] + red[1][threadIdx.x] +
            red[2][threadIdx.x] + red[3][threadIdx.x];
    }
}

// ---------------------------------------------------------------------------
// Kernel 2 (fused solve+emit). Lanes 0-13 / 64-68 reduce the row's slice
// partials into LDS in parallel; thread 0 does the closed-form 2x2 SPD OT
// solve in f64 and broadcasts 10 f32 coefficients via LDS. All threads issue
// their geo loads BEFORE the barriers so the serial solve hides under load
// latency. Emit:
//   f[b,n] = cxx(x^2-Ex2) + cyy(y^2-Ey2) + cxy(xy-Exy) + cx(x-Ex) + cy(y-Ey)
// with nontemporal float4 stores (write-once; keep L3 for a/b).
// Grid (N/4096, B), 4 float4 per thread.
// ---------------------------------------------------------------------------
__global__ __launch_bounds__(TPB) void kemit(const float* __restrict__ gx,
                                             const double* __restrict__ spart,
                                             const double* __restrict__ gpart,
                                             int N, float* __restrict__ out) {
    const int b = blockIdx.y;
    __shared__ double sh14[14];
    __shared__ double shg[5];
    __shared__ float shc[10];

    // issue geo loads first — independent of the coefficient solve
    const f4* gx4 = reinterpret_cast<const f4*>(gx);
    const int i0 = blockIdx.x * (TPB * 4) + threadIdx.x;
    f4 g[8];
#pragma unroll
    for (int k = 0; k < 4; k++) {
        g[2 * k]     = gx4[2 * (i0 + k * TPB)];
        g[2 * k + 1] = gx4[2 * (i0 + k * TPB) + 1];
    }

    // parallel reduce of slice partials into LDS
    if (threadIdx.x < 14) {
        double t = 0;
#pragma unroll
        for (int s = 0; s < NSLICE; s++)
            t += spart[((size_t)b * NSLICE + s) * 14 + threadIdx.x];
        sh14[threadIdx.x] = t;
    } else if (threadIdx.x >= 64 && threadIdx.x < 69) {
        double t = 0;
#pragma unroll
        for (int s = 0; s < NSLICE; s++) t += gpart[s * 5 + (threadIdx.x - 64)];
        shg[threadIdx.x - 64] = t / (double)N;
    }
    __syncthreads();

    if (threadIdx.x == 0) {
        double Sa = sh14[0],  mx  = sh14[1],  my  = sh14[2],  Saxx = sh14[3],  Saxy = sh14[4],  Sayy = sh14[5],  Saa = sh14[6];
        double Sb = sh14[7],  mbx = sh14[8],  mby = sh14[9],  Sbxx = sh14[10], Sbxy = sh14[11], Sbyy = sh14[12], Sbb = sh14[13];

        double da = 1.0 - Saa, db = 1.0 - Sbb;
        // cov = (Σ w p p' - m m' (2 - Σw)) / denom (exact expansion of centered sum)
        double Caxx = (Saxx - mx * mx * (2.0 - Sa)) / da;
        double Caxy = (Saxy - mx * my * (2.0 - Sa)) / da;
        double Cayy = (Sayy - my * my * (2.0 - Sa)) / da;
        double Cbxx = (Sbxx - mbx * mbx * (2.0 - Sb)) / db;
        double Cbxy = (Sbxy - mbx * mby * (2.0 - Sb)) / db;
        double Cbyy = (Sbyy - mby * mby * (2.0 - Sb)) / db;

        // R = sqrt(cov_a) = (C + sqrt(det C) I) / sqrt(tr C + 2 sqrt(det C))
        double s0 = sqrt(fmax(Caxx * Cayy - Caxy * Caxy, 0.0));
        double t0 = sqrt(Caxx + Cayy + 2.0 * s0);
        double Rxx = (Caxx + s0) / t0, Rxy = Caxy / t0, Ryy = (Cayy + s0) / t0;
        double detR = Rxx * Ryy - Rxy * Rxy;
        double Ixx = Ryy / detR, Ixy = -Rxy / detR, Iyy = Rxx / detR;  // R^{-1}

        // mid = R cov_b R (symmetric)
        double Txx = Cbxx * Rxx + Cbxy * Rxy;
        double Txy = Cbxx * Rxy + Cbxy * Ryy;
        double Tyx = Cbxy * Rxx + Cbyy * Rxy;
        double Tyy = Cbxy * Rxy + Cbyy * Ryy;
        double midxx = Rxx * Txx + Rxy * Tyx;
        double midyy = Rxy * Txy + Ryy * Tyy;
        double midxy = 0.5 * ((Rxx * Txy + Rxy * Tyy) + (Rxy * Txx + Ryy * Tyx));

        // M = sqrt(mid)
        double s1 = sqrt(fmax(midxx * midyy - midxy * midxy, 0.0));
        double t1 = sqrt(midxx + midyy + 2.0 * s1);
        double Mxx = (midxx + s1) / t1, Mxy = midxy / t1, Myy = (midyy + s1) / t1;

        // A = R^{-1} M R^{-1}
        double Uxx = Mxx * Ixx + Mxy * Ixy;
        double Uxy = Mxx * Ixy + Mxy * Iyy;
        double Uyx = Mxy * Ixx + Myy * Ixy;
        double Uyy = Mxy * Ixy + Myy * Iyy;
        double Axx = Ixx * Uxx + Ixy * Uyx;
        double Axy = Ixx * Uxy + Ixy * Uyy;
        double Ayy = Ixy * Uxy + Iyy * Uyy;

        // quadratic-form coefficients; row-mean subtraction cancels the const
        shc[0] = (float)(1.0 - Axx);
        shc[1] = (float)(1.0 - Ayy);
        shc[2] = (float)(-2.0 * Axy);
        shc[3] = (float)(2.0 * (Axx * mx + Axy * my - mbx));
        shc[4] = (float)(2.0 * (Ayy * my + Axy * mx - mby));
        shc[5] = (float)shg[0];
        shc[6] = (float)shg[1];
        shc[7] = (float)shg[2];
        shc[8] = (float)shg[3];
        shc[9] = (float)shg[4];
    }
    __syncthreads();

    const float cxx = shc[0], cyy = shc[1], cxy = shc[2], cx = shc[3], cy = shc[4];
    const float Ex = shc[5], Ey = shc[6], Ex2 = shc[7], Exy = shc[8], Ey2 = shc[9];

    f4* out4 = reinterpret_cast<f4*>(out + (size_t)b * N);
#pragma unroll
    for (int k = 0; k < 4; k++) {
        int i = i0 + k * TPB;
        f4 g0 = g[2 * k], g1 = g[2 * k + 1];
        float rx[4] = {g0[0], g0[2], g1[0], g1[2]};
        float ry[4] = {g0[1], g0[3], g1[1], g1[3]};
        f4 o;
#pragma unroll
        for (int j = 0; j < 4; j++) {
            float x = rx[j], y = ry[j];
            o[j] = cxx * (x * x - Ex2) + cyy * (y * y - Ey2) + cxy * (x * y - Exy) +
                   cx * (x - Ex) + cy * (y - Ey);
        }
        __builtin_nontemporal_store(o, out4 + i);
    }
}

// ---------------------------------------------------------------------------
extern "C" void kernel_launch(void* const* d_in, const int* in_sizes, int n_in,
                              void* d_out, int out_size, void* d_ws, size_t ws_size,
                              hipStream_t stream) {
    const float* geo_x = (const float*)d_in[0];
    const float* geo_y = (const float*)d_in[1];
    const float* a     = (const float*)d_in[2];
    const float* b     = (const float*)d_in[3];
    float* out = (float*)d_out;

    int N = in_sizes[0] / 2;       // 16384
    int B = in_sizes[2] / N;       // 512

    char* ws = (char*)d_ws;
    double* gpart = (double*)ws;                                   // NSLICE*5 doubles
    double* spart = (double*)(ws + 512);                           // B*NSLICE*14 doubles

    kstats<<<dim3(NSLICE, B / ROWS + 1), TPB, 0, stream>>>(geo_x, geo_y, a, b, N, B,
                                                           spart, gpart);
    kemit<<<dim3((N / 4) / (TPB * 4), B), TPB, 0, stream>>>(geo_x, spart, gpart, N, out);
}

// Round 9
// 31.070 us; speedup vs baseline: 4.1020x; 1.8178x over previous
//
#include <hip/hip_runtime.h>

static constexpr int TPB = 256;
static constexpr int NSLICE = 4;   // slices per batch row

using f4 = __attribute__((ext_vector_type(4))) float;
using f2 = __attribute__((ext_vector_type(2))) float;

__device__ __forceinline__ float wave_reduce_f32(float v) {
#pragma unroll
    for (int off = 32; off > 0; off >>= 1)
        v += __shfl_down(v, off, 64);
    return v;
}

// ---------------------------------------------------------------------------
// Kernel 1: per-(batch,slice) weighted moment partial sums, PACKED-F32 form.
// Grid (NSLICE, B+1). Row b<B, slice s: spart[(b*NSLICE+s)*12 + {0..11}] =
//   Sax, Say, Saxx, Saxy, Sayy, Saa   (weights a, geo_x)
//   Sbx, Sby, Sbxx, Sbxy, Sbyy, Sbb   (weights b, geo_y)
// Sa and Sb are NOT accumulated: rows of a/b are normalized (sum==1 to f32
// rounding); solver uses Sa=Sb=1 (error ~1e-7 << 3.6e-4 threshold).
// Row b==B: unweighted geo_x moment partials -> gpart[s*5 + {x,y,xx,xy,yy}].
// Points are processed as float2 PAIRS so the backend can emit v_pk_fma_f32 /
// v_pk_add_f32 / v_pk_mul_f32 (full-rate packed f32 on gfx950) — ~3x fewer
// VALU issue slots than the scalar form (kstats was VALU-issue-bound).
// Two light passes (a*gx then b*gy) keep live VGPRs ~50 (<64) so we hold
// 8 blocks/CU under launch_bounds(256,8) with NO scratch demotion (R7 lesson:
// >20 f32 accumulators in one loop -> scratch, 74MB of spill traffic).
// ---------------------------------------------------------------------------
__global__ __launch_bounds__(TPB, 8) void kstats(const float* __restrict__ gx,
                                                 const float* __restrict__ gy,
                                                 const float* __restrict__ a,
                                                 const float* __restrict__ bw,
                                                 int N, int B,
                                                 double* __restrict__ spart,
                                                 double* __restrict__ gpart) {
    const int s = blockIdx.x;
    const int b = blockIdx.y;
    const int n4   = N / 4;          // float4 groups per row
    const int per  = n4 / NSLICE;    // groups per slice
    const int base = s * per;
    const f4* gx4 = reinterpret_cast<const f4*>(gx);
    const int lane = threadIdx.x & 63, wid = threadIdx.x >> 6;

    if (b == B) {
        // unweighted geo_x moments for this slice
        float sx = 0, sy = 0, sxx = 0, sxy = 0, syy = 0;
        for (int i = base + threadIdx.x; i < base + per; i += TPB) {
            f4 g0 = gx4[2 * i], g1 = gx4[2 * i + 1];
            float x0 = g0[0], y0 = g0[1], x1 = g0[2], y1 = g0[3];
            float x2 = g1[0], y2 = g1[1], x3 = g1[2], y3 = g1[3];
            sx  += (x0 + x1) + (x2 + x3);
            sy  += (y0 + y1) + (y2 + y3);
            sxx += x0 * x0 + x1 * x1 + x2 * x2 + x3 * x3;
            sxy += x0 * y0 + x1 * y1 + x2 * y2 + x3 * y3;
            syy += y0 * y0 + y1 * y1 + y2 * y2 + y3 * y3;
        }
        float accg[5] = {sx, sy, sxx, sxy, syy};
        __shared__ double redg[4][5];
#pragma unroll
        for (int k = 0; k < 5; k++) {
            float v = wave_reduce_f32(accg[k]);
            if (lane == 0) redg[wid][k] = (double)v;
        }
        __syncthreads();
        if (threadIdx.x < 5)
            gpart[s * 5 + threadIdx.x] = redg[0][threadIdx.x] + redg[1][threadIdx.x] +
                                         redg[2][threadIdx.x] + redg[3][threadIdx.x];
        return;
    }

    const f4* a4  = reinterpret_cast<const f4*>(a  + (size_t)b * N);
    const f4* b4  = reinterpret_cast<const f4*>(bw + (size_t)b * N);
    const f4* gy4 = reinterpret_cast<const f4*>(gy);

    const f2 z2 = {0.0f, 0.0f};
    f2 acc[12];
#pragma unroll
    for (int k = 0; k < 12; k++) acc[k] = z2;

    // ---- pass A: weights a against geo_x ----
#pragma unroll 2
    for (int i = base + threadIdx.x; i < base + per; i += TPB) {
        f4 av = a4[i];
        f4 g0 = gx4[2 * i], g1 = gx4[2 * i + 1];
#pragma unroll
        for (int h = 0; h < 2; h++) {
            f2 w = (h == 0) ? f2{av[0], av[1]} : f2{av[2], av[3]};
            f2 x = (h == 0) ? f2{g0[0], g0[2]} : f2{g1[0], g1[2]};
            f2 y = (h == 0) ? f2{g0[1], g0[3]} : f2{g1[1], g1[3]};
            f2 wx = w * x, wy = w * y;
            acc[0] += wx;          // Sax
            acc[1] += wy;          // Say
            acc[2] += wx * x;      // Saxx
            acc[3] += wx * y;      // Saxy
            acc[4] += wy * y;      // Sayy
            acc[5] += w * w;       // Saa
        }
    }

    // ---- pass B: weights b against geo_y ----
#pragma unroll 2
    for (int i = base + threadIdx.x; i < base + per; i += TPB) {
        f4 bv = b4[i];
        f4 h0 = gy4[2 * i], h1 = gy4[2 * i + 1];
#pragma unroll
        for (int h = 0; h < 2; h++) {
            f2 w = (h == 0) ? f2{bv[0], bv[1]} : f2{bv[2], bv[3]};
            f2 x = (h == 0) ? f2{h0[0], h0[2]} : f2{h1[0], h1[2]};
            f2 y = (h == 0) ? f2{h0[1], h0[3]} : f2{h1[1], h1[3]};
            f2 wx = w * x, wy = w * y;
            acc[6]  += wx;         // Sbx
            acc[7]  += wy;         // Sby
            acc[8]  += wx * x;     // Sbxx
            acc[9]  += wx * y;     // Sbxy
            acc[10] += wy * y;     // Sbyy
            acc[11] += w * w;      // Sbb
        }
    }

    __shared__ double red[4][12];
#pragma unroll
    for (int k = 0; k < 12; k++) {
        float v = wave_reduce_f32(acc[k][0] + acc[k][1]);
        if (lane == 0) red[wid][k] = (double)v;
    }
    __syncthreads();
    if (threadIdx.x < 12) {
        spart[((size_t)b * NSLICE + s) * 12 + threadIdx.x] =
            red[0][threadIdx.x] + red[1][threadIdx.x] +
            red[2][threadIdx.x] + red[3][threadIdx.x];
    }
}

// ---------------------------------------------------------------------------
// Kernel 2 (fused solve+emit), unchanged structure from the proven R5 kernel.
// Lanes 0-11 / 64-68 reduce the row's slice partials into LDS in parallel;
// thread 0 does the closed-form 2x2 SPD OT solve in f64 (with Sa=Sb=1) and
// broadcasts 10 f32 coefficients via LDS. All threads issue their geo loads
// BEFORE the barriers so the serial solve hides under load latency. Emit:
//   f[b,n] = cxx(x^2-Ex2) + cyy(y^2-Ey2) + cxy(xy-Exy) + cx(x-Ex) + cy(y-Ey)
// with nontemporal float4 stores (write-once; keep L3 for a/b).
// Grid (N/4096, B), 4 float4 per thread.
// ---------------------------------------------------------------------------
__global__ __launch_bounds__(TPB) void kemit(const float* __restrict__ gx,
                                             const double* __restrict__ spart,
                                             const double* __restrict__ gpart,
                                             int N, float* __restrict__ out) {
    const int b = blockIdx.y;
    __shared__ double sh12[12];
    __shared__ double shg[5];
    __shared__ float shc[10];

    // issue geo loads first — independent of the coefficient solve
    const f4* gx4 = reinterpret_cast<const f4*>(gx);
    const int i0 = blockIdx.x * (TPB * 4) + threadIdx.x;
    f4 g[8];
#pragma unroll
    for (int k = 0; k < 4; k++) {
        g[2 * k]     = gx4[2 * (i0 + k * TPB)];
        g[2 * k + 1] = gx4[2 * (i0 + k * TPB) + 1];
    }

    // parallel reduce of slice partials into LDS
    if (threadIdx.x < 12) {
        double t = 0;
#pragma unroll
        for (int s = 0; s < NSLICE; s++)
            t += spart[((size_t)b * NSLICE + s) * 12 + threadIdx.x];
        sh12[threadIdx.x] = t;
    } else if (threadIdx.x >= 64 && threadIdx.x < 69) {
        double t = 0;
#pragma unroll
        for (int s = 0; s < NSLICE; s++) t += gpart[s * 5 + (threadIdx.x - 64)];
        shg[threadIdx.x - 64] = t / (double)N;
    }
    __syncthreads();

    if (threadIdx.x == 0) {
        double mx  = sh12[0],  my  = sh12[1],  Saxx = sh12[2],  Saxy = sh12[3],  Sayy = sh12[4],  Saa = sh12[5];
        double mbx = sh12[6],  mby = sh12[7],  Sbxx = sh12[8],  Sbxy = sh12[9],  Sbyy = sh12[10], Sbb = sh12[11];

        double da = 1.0 - Saa, db = 1.0 - Sbb;
        // cov = (Σ w p p' - m m') / denom  (Sa = Sb = 1: rows are normalized)
        double Caxx = (Saxx - mx * mx) / da;
        double Caxy = (Saxy - mx * my) / da;
        double Cayy = (Sayy - my * my) / da;
        double Cbxx = (Sbxx - mbx * mbx) / db;
        double Cbxy = (Sbxy - mbx * mby) / db;
        double Cbyy = (Sbyy - mby * mby) / db;

        // R = sqrt(cov_a) = (C + sqrt(det C) I) / sqrt(tr C + 2 sqrt(det C))
        double s0 = sqrt(fmax(Caxx * Cayy - Caxy * Caxy, 0.0));
        double t0 = sqrt(Caxx + Cayy + 2.0 * s0);
        double Rxx = (Caxx + s0) / t0, Rxy = Caxy / t0, Ryy = (Cayy + s0) / t0;
        double detR = Rxx * Ryy - Rxy * Rxy;
        double Ixx = Ryy / detR, Ixy = -Rxy / detR, Iyy = Rxx / detR;  // R^{-1}

        // mid = R cov_b R (symmetric)
        double Txx = Cbxx * Rxx + Cbxy * Rxy;
        double Txy = Cbxx * Rxy + Cbxy * Ryy;
        double Tyx = Cbxy * Rxx + Cbyy * Rxy;
        double Tyy = Cbxy * Rxy + Cbyy * Ryy;
        double midxx = Rxx * Txx + Rxy * Tyx;
        double midyy = Rxy * Txy + Ryy * Tyy;
        double midxy = 0.5 * ((Rxx * Txy + Rxy * Tyy) + (Rxy * Txx + Ryy * Tyx));

        // M = sqrt(mid)
        double s1 = sqrt(fmax(midxx * midyy - midxy * midxy, 0.0));
        double t1 = sqrt(midxx + midyy + 2.0 * s1);
        double Mxx = (midxx + s1) / t1, Mxy = midxy / t1, Myy = (midyy + s1) / t1;

        // A = R^{-1} M R^{-1}
        double Uxx = Mxx * Ixx + Mxy * Ixy;
        double Uxy = Mxx * Ixy + Mxy * Iyy;
        double Uyx = Mxy * Ixx + Myy * Ixy;
        double Uyy = Mxy * Ixy + Myy * Iyy;
        double Axx = Ixx * Uxx + Ixy * Uyx;
        double Axy = Ixx * Uxy + Ixy * Uyy;
        double Ayy = Ixy * Uxy + Iyy * Uyy;

        // quadratic-form coefficients; row-mean subtraction cancels the const
        shc[0] = (float)(1.0 - Axx);
        shc[1] = (float)(1.0 - Ayy);
        shc[2] = (float)(-2.0 * Axy);
        shc[3] = (float)(2.0 * (Axx * mx + Axy * my - mbx));
        shc[4] = (float)(2.0 * (Ayy * my + Axy * mx - mby));
        shc[5] = (float)shg[0];
        shc[6] = (float)shg[1];
        shc[7] = (float)shg[2];
        shc[8] = (float)shg[3];
        shc[9] = (float)shg[4];
    }
    __syncthreads();

    const float cxx = shc[0], cyy = shc[1], cxy = shc[2], cx = shc[3], cy = shc[4];
    const float Ex = shc[5], Ey = shc[6], Ex2 = shc[7], Exy = shc[8], Ey2 = shc[9];

    f4* out4 = reinterpret_cast<f4*>(out + (size_t)b * N);
#pragma unroll
    for (int k = 0; k < 4; k++) {
        int i = i0 + k * TPB;
        f4 g0 = g[2 * k], g1 = g[2 * k + 1];
        float rx[4] = {g0[0], g0[2], g1[0], g1[2]};
        float ry[4] = {g0[1], g0[3], g1[1], g1[3]};
        f4 o;
#pragma unroll
        for (int j = 0; j < 4; j++) {
            float x = rx[j], y = ry[j];
            o[j] = cxx * (x * x - Ex2) + cyy * (y * y - Ey2) + cxy * (x * y - Exy) +
                   cx * (x - Ex) + cy * (y - Ey);
        }
        __builtin_nontemporal_store(o, out4 + i);
    }
}

// ---------------------------------------------------------------------------
extern "C" void kernel_launch(void* const* d_in, const int* in_sizes, int n_in,
                              void* d_out, int out_size, void* d_ws, size_t ws_size,
                              hipStream_t stream) {
    const float* geo_x = (const float*)d_in[0];
    const float* geo_y = (const float*)d_in[1];
    const float* a     = (const float*)d_in[2];
    const float* b     = (const float*)d_in[3];
    float* out = (float*)d_out;

    int N = in_sizes[0] / 2;       // 16384
    int B = in_sizes[2] / N;       // 512

    char* ws = (char*)d_ws;
    double* gpart = (double*)ws;                                   // NSLICE*5 doubles
    double* spart = (double*)(ws + 512);                           // B*NSLICE*12 doubles

    kstats<<<dim3(NSLICE, B + 1), TPB, 0, stream>>>(geo_x, geo_y, a, b, N, B,
                                                    spart, gpart);
    kemit<<<dim3((N / 4) / (TPB * 4), B), TPB, 0, stream>>>(geo_x, spart, gpart, N, out);
}

// Round 10
// 26.200 us; speedup vs baseline: 4.8644x; 1.1859x over previous
//
#include <hip/hip_runtime.h>

static constexpr int TPB = 256;
static constexpr int NSLICE = 4;   // slices per batch row

using f4 = __attribute__((ext_vector_type(4))) float;

__device__ __forceinline__ float wave_reduce_f32(float v) {
#pragma unroll
    for (int off = 32; off > 0; off >>= 1)
        v += __shfl_down(v, off, 64);
    return v;
}

// ---------------------------------------------------------------------------
// Kernel 1: per-(batch,slice) weighted moment partial sums. Grid (NSLICE,B+1).
// Row b<B, slice s: spart[(b*NSLICE+s)*12 + {0..11}] =
//   Sax, Say, Saxx, Saxy, Sayy, Saa   (weights a, geo_x)
//   Sbx, Sby, Sbxx, Sbxy, Sbyy, Sbb   (weights b, geo_y)
// Sa/Sb not accumulated (rows normalized; solver uses Sa=Sb=1 — validated R9).
// Row b==B: unweighted geo_x moment partials -> gpart[s*5 + {x,y,xx,xy,yy}].
//
// MLP-focused structure (R9 lesson: kstats is latency-bound, NOT VALU-bound;
// two-pass halved loads-in-flight and regressed): each thread's 4 iterations
// are fully unrolled as TWO explicit batches of 12 f4 loads -> compute, so
// ~12 vector loads are outstanding per wave instead of ~6. Plain launch
// bounds: let the allocator take ~100-130 VGPR (4-6 waves/SIMD); grid 2052
// blocks still fills the machine.
// ---------------------------------------------------------------------------
__global__ __launch_bounds__(TPB) void kstats(const float* __restrict__ gx,
                                              const float* __restrict__ gy,
                                              const float* __restrict__ a,
                                              const float* __restrict__ bw,
                                              int N, int B,
                                              double* __restrict__ spart,
                                              double* __restrict__ gpart) {
    const int s = blockIdx.x;
    const int b = blockIdx.y;
    const int n4   = N / 4;          // float4 groups per row
    const int per  = n4 / NSLICE;    // groups per slice (1024)
    const int base = s * per;
    const f4* gx4 = reinterpret_cast<const f4*>(gx);
    const int lane = threadIdx.x & 63, wid = threadIdx.x >> 6;

    if (b == B) {
        // unweighted geo_x moments for this slice
        float sx = 0, sy = 0, sxx = 0, sxy = 0, syy = 0;
        for (int i = base + threadIdx.x; i < base + per; i += TPB) {
            f4 g0 = gx4[2 * i], g1 = gx4[2 * i + 1];
            float x0 = g0[0], y0 = g0[1], x1 = g0[2], y1 = g0[3];
            float x2 = g1[0], y2 = g1[1], x3 = g1[2], y3 = g1[3];
            sx  += (x0 + x1) + (x2 + x3);
            sy  += (y0 + y1) + (y2 + y3);
            sxx += x0 * x0 + x1 * x1 + x2 * x2 + x3 * x3;
            sxy += x0 * y0 + x1 * y1 + x2 * y2 + x3 * y3;
            syy += y0 * y0 + y1 * y1 + y2 * y2 + y3 * y3;
        }
        float accg[5] = {sx, sy, sxx, sxy, syy};
        __shared__ double redg[4][5];
#pragma unroll
        for (int k = 0; k < 5; k++) {
            float v = wave_reduce_f32(accg[k]);
            if (lane == 0) redg[wid][k] = (double)v;
        }
        __syncthreads();
        if (threadIdx.x < 5)
            gpart[s * 5 + threadIdx.x] = redg[0][threadIdx.x] + redg[1][threadIdx.x] +
                                         redg[2][threadIdx.x] + redg[3][threadIdx.x];
        return;
    }

    const f4* a4  = reinterpret_cast<const f4*>(a  + (size_t)b * N);
    const f4* b4  = reinterpret_cast<const f4*>(bw + (size_t)b * N);
    const f4* gy4 = reinterpret_cast<const f4*>(gy);

    float acc[12];
#pragma unroll
    for (int k = 0; k < 12; k++) acc[k] = 0.0f;

    // exactly 4 iterations/thread (per==1024, TPB==256): two batches of 2.
    const int i0 = base + threadIdx.x;

#pragma unroll
    for (int half = 0; half < 2; half++) {
        const int ia = i0 + (2 * half) * TPB;
        const int ib = i0 + (2 * half + 1) * TPB;
        // ---- batch: issue 12 independent f4 loads ----
        f4 av0 = a4[ia],  av1 = a4[ib];
        f4 bv0 = b4[ia],  bv1 = b4[ib];
        f4 gA0 = gx4[2 * ia], gA1 = gx4[2 * ia + 1];
        f4 gB0 = gx4[2 * ib], gB1 = gx4[2 * ib + 1];
        f4 hA0 = gy4[2 * ia], hA1 = gy4[2 * ia + 1];
        f4 hB0 = gy4[2 * ib], hB1 = gy4[2 * ib + 1];

        // ---- compute both iterations ----
#pragma unroll
        for (int q = 0; q < 2; q++) {
            f4 av = q ? av1 : av0;
            f4 bv = q ? bv1 : bv0;
            f4 g0 = q ? gB0 : gA0, g1 = q ? gB1 : gA1;
            f4 h0 = q ? hB0 : hA0, h1 = q ? hB1 : hA1;
            float wa[4] = {av[0], av[1], av[2], av[3]};
            float wb[4] = {bv[0], bv[1], bv[2], bv[3]};
            float px[4] = {g0[0], g0[2], g1[0], g1[2]};
            float py[4] = {g0[1], g0[3], g1[1], g1[3]};
            float qx[4] = {h0[0], h0[2], h1[0], h1[2]};
            float qy[4] = {h0[1], h0[3], h1[1], h1[3]};
#pragma unroll
            for (int j = 0; j < 4; j++) {
                float w = wa[j], x = px[j], y = py[j];
                float wx = w * x, wy = w * y;
                acc[0] += wx;
                acc[1] += wy;
                acc[2] += wx * x;
                acc[3] += wx * y;
                acc[4] += wy * y;
                acc[5] += w * w;
                float v = wb[j], u = qx[j], t = qy[j];
                float vu = v * u, vt = v * t;
                acc[6]  += vu;
                acc[7]  += vt;
                acc[8]  += vu * u;
                acc[9]  += vu * t;
                acc[10] += vt * t;
                acc[11] += v * v;
            }
        }
    }

    __shared__ double red[4][12];
#pragma unroll
    for (int k = 0; k < 12; k++) {
        float v = wave_reduce_f32(acc[k]);
        if (lane == 0) red[wid][k] = (double)v;
    }
    __syncthreads();
    if (threadIdx.x < 12) {
        spart[((size_t)b * NSLICE + s) * 12 + threadIdx.x] =
            red[0][threadIdx.x] + red[1][threadIdx.x] +
            red[2][threadIdx.x] + red[3][threadIdx.x];
    }
}

// ---------------------------------------------------------------------------
// Kernel 2 (fused solve+emit), proven R5/R9 structure. Lanes 0-11 / 64-68
// reduce the row's slice partials into LDS in parallel; thread 0 does the
// closed-form 2x2 SPD OT solve in f64 (Sa=Sb=1) and broadcasts 10 f32
// coefficients via LDS. Geo loads issued BEFORE the barriers so the serial
// solve hides under load latency. Emit:
//   f[b,n] = cxx(x^2-Ex2) + cyy(y^2-Ey2) + cxy(xy-Exy) + cx(x-Ex) + cy(y-Ey)
// with nontemporal float4 stores. Grid (N/4096, B), 4 float4 per thread.
// ---------------------------------------------------------------------------
__global__ __launch_bounds__(TPB) void kemit(const float* __restrict__ gx,
                                             const double* __restrict__ spart,
                                             const double* __restrict__ gpart,
                                             int N, float* __restrict__ out) {
    const int b = blockIdx.y;
    __shared__ double sh12[12];
    __shared__ double shg[5];
    __shared__ float shc[10];

    // issue geo loads first — independent of the coefficient solve
    const f4* gx4 = reinterpret_cast<const f4*>(gx);
    const int i0 = blockIdx.x * (TPB * 4) + threadIdx.x;
    f4 g[8];
#pragma unroll
    for (int k = 0; k < 4; k++) {
        g[2 * k]     = gx4[2 * (i0 + k * TPB)];
        g[2 * k + 1] = gx4[2 * (i0 + k * TPB) + 1];
    }

    // parallel reduce of slice partials into LDS
    if (threadIdx.x < 12) {
        double t = 0;
#pragma unroll
        for (int s = 0; s < NSLICE; s++)
            t += spart[((size_t)b * NSLICE + s) * 12 + threadIdx.x];
        sh12[threadIdx.x] = t;
    } else if (threadIdx.x >= 64 && threadIdx.x < 69) {
        double t = 0;
#pragma unroll
        for (int s = 0; s < NSLICE; s++) t += gpart[s * 5 + (threadIdx.x - 64)];
        shg[threadIdx.x - 64] = t / (double)N;
    }
    __syncthreads();

    if (threadIdx.x == 0) {
        double mx  = sh12[0],  my  = sh12[1],  Saxx = sh12[2],  Saxy = sh12[3],  Sayy = sh12[4],  Saa = sh12[5];
        double mbx = sh12[6],  mby = sh12[7],  Sbxx = sh12[8],  Sbxy = sh12[9],  Sbyy = sh12[10], Sbb = sh12[11];

        double da = 1.0 - Saa, db = 1.0 - Sbb;
        // cov = (Σ w p p' - m m') / denom  (Sa = Sb = 1: rows are normalized)
        double Caxx = (Saxx - mx * mx) / da;
        double Caxy = (Saxy - mx * my) / da;
        double Cayy = (Sayy - my * my) / da;
        double Cbxx = (Sbxx - mbx * mbx) / db;
        double Cbxy = (Sbxy - mbx * mby) / db;
        double Cbyy = (Sbyy - mby * mby) / db;

        // R = sqrt(cov_a) = (C + sqrt(det C) I) / sqrt(tr C + 2 sqrt(det C))
        double s0 = sqrt(fmax(Caxx * Cayy - Caxy * Caxy, 0.0));
        double t0 = sqrt(Caxx + Cayy + 2.0 * s0);
        double Rxx = (Caxx + s0) / t0, Rxy = Caxy / t0, Ryy = (Cayy + s0) / t0;
        double detR = Rxx * Ryy - Rxy * Rxy;
        double Ixx = Ryy / detR, Ixy = -Rxy / detR, Iyy = Rxx / detR;  // R^{-1}

        // mid = R cov_b R (symmetric)
        double Txx = Cbxx * Rxx + Cbxy * Rxy;
        double Txy = Cbxx * Rxy + Cbxy * Ryy;
        double Tyx = Cbxy * Rxx + Cbyy * Rxy;
        double Tyy = Cbxy * Rxy + Cbyy * Ryy;
        double midxx = Rxx * Txx + Rxy * Tyx;
        double midyy = Rxy * Txy + Ryy * Tyy;
        double midxy = 0.5 * ((Rxx * Txy + Rxy * Tyy) + (Rxy * Txx + Ryy * Tyx));

        // M = sqrt(mid)
        double s1 = sqrt(fmax(midxx * midyy - midxy * midxy, 0.0));
        double t1 = sqrt(midxx + midyy + 2.0 * s1);
        double Mxx = (midxx + s1) / t1, Mxy = midxy / t1, Myy = (midyy + s1) / t1;

        // A = R^{-1} M R^{-1}
        double Uxx = Mxx * Ixx + Mxy * Ixy;
        double Uxy = Mxx * Ixy + Mxy * Iyy;
        double Uyx = Mxy * Ixx + Myy * Ixy;
        double Uyy = Mxy * Ixy + Myy * Iyy;
        double Axx = Ixx * Uxx + Ixy * Uyx;
        double Axy = Ixx * Uxy + Ixy * Uyy;
        double Ayy = Ixy * Uxy + Iyy * Uyy;

        // quadratic-form coefficients; row-mean subtraction cancels the const
        shc[0] = (float)(1.0 - Axx);
        shc[1] = (float)(1.0 - Ayy);
        shc[2] = (float)(-2.0 * Axy);
        shc[3] = (float)(2.0 * (Axx * mx + Axy * my - mbx));
        shc[4] = (float)(2.0 * (Ayy * my + Axy * mx - mby));
        shc[5] = (float)shg[0];
        shc[6] = (float)shg[1];
        shc[7] = (float)shg[2];
        shc[8] = (float)shg[3];
        shc[9] = (float)shg[4];
    }
    __syncthreads();

    const float cxx = shc[0], cyy = shc[1], cxy = shc[2], cx = shc[3], cy = shc[4];
    const float Ex = shc[5], Ey = shc[6], Ex2 = shc[7], Exy = shc[8], Ey2 = shc[9];

    f4* out4 = reinterpret_cast<f4*>(out + (size_t)b * N);
#pragma unroll
    for (int k = 0; k < 4; k++) {
        int i = i0 + k * TPB;
        f4 g0 = g[2 * k], g1 = g[2 * k + 1];
        float rx[4] = {g0[0], g0[2], g1[0], g1[2]};
        float ry[4] = {g0[1], g0[3], g1[1], g1[3]};
        f4 o;
#pragma unroll
        for (int j = 0; j < 4; j++) {
            float x = rx[j], y = ry[j];
            o[j] = cxx * (x * x - Ex2) + cyy * (y * y - Ey2) + cxy * (x * y - Exy) +
                   cx * (x - Ex) + cy * (y - Ey);
        }
        __builtin_nontemporal_store(o, out4 + i);
    }
}

// ---------------------------------------------------------------------------
extern "C" void kernel_launch(void* const* d_in, const int* in_sizes, int n_in,
                              void* d_out, int out_size, void* d_ws, size_t ws_size,
                              hipStream_t stream) {
    const float* geo_x = (const float*)d_in[0];
    const float* geo_y = (const float*)d_in[1];
    const float* a     = (const float*)d_in[2];
    const float* b     = (const float*)d_in[3];
    float* out = (float*)d_out;

    int N = in_sizes[0] / 2;       // 16384
    int B = in_sizes[2] / N;       // 512

    char* ws = (char*)d_ws;
    double* gpart = (double*)ws;                                   // NSLICE*5 doubles
    double* spart = (double*)(ws + 512);                           // B*NSLICE*12 doubles

    kstats<<<dim3(NSLICE, B + 1), TPB, 0, stream>>>(geo_x, geo_y, a, b, N, B,
                                                    spart, gpart);
    kemit<<<dim3((N / 4) / (TPB * 4), B), TPB, 0, stream>>>(geo_x, spart, gpart, N, out);
}